// Round 1
// baseline (509.599 us; speedup 1.0000x reference)
//
#include <hip/hip_runtime.h>
#include <stdint.h>

typedef unsigned short u16t;
typedef __attribute__((ext_vector_type(8))) short short8;
typedef __attribute__((ext_vector_type(4))) float floatx4;

__device__ __forceinline__ float bf2f(u16t u) {
  union { unsigned int i; float f; } v; v.i = ((unsigned int)u) << 16; return v.f;
}
__device__ __forceinline__ u16t f2bf(float f) {
  union { float f; unsigned int i; } v; v.f = f;
  unsigned int x = v.i;
  return (u16t)((x + 0x7fffu + ((x >> 16) & 1u)) >> 16);  // RNE, no NaN inputs here
}
__device__ __forceinline__ void async_copy16(const void* g, void* l) {
  __builtin_amdgcn_global_load_lds(
      (const __attribute__((address_space(1))) void*)g,
      (__attribute__((address_space(3))) void*)l, 16, 0, 0);
}

// ---------------- prep: x fp32 -> dec[:, :256] bf16  +  xT[B][D][T] bf16 ----
__global__ __launch_bounds__(256) void prep_x(const float* __restrict__ x,
                                              u16t* __restrict__ dec,
                                              u16t* __restrict__ xT) {
  __shared__ u16t tile[64 * 65];
  const int tid = threadIdx.x;
  const int b = blockIdx.z, t0 = blockIdx.y * 64, d0 = blockIdx.x * 64;
  const int r = tid >> 2, cb = (tid & 3) << 4;
  const float* gx = x + ((size_t)(b * 2048 + t0 + r) * 256 + d0 + cb);
  union { uint4 v[2]; u16t u[16]; } pk;
#pragma unroll
  for (int j = 0; j < 16; j += 4) {
    float4 f = *(const float4*)(gx + j);
    pk.u[j + 0] = f2bf(f.x); pk.u[j + 1] = f2bf(f.y);
    pk.u[j + 2] = f2bf(f.z); pk.u[j + 3] = f2bf(f.w);
  }
  u16t* gd = dec + ((size_t)(b * 2048 + t0 + r) * 512 + d0 + cb);
  *(uint4*)(gd) = pk.v[0];
  *(uint4*)(gd + 8) = pk.v[1];
#pragma unroll
  for (int j = 0; j < 16; ++j) tile[r * 65 + cb + j] = pk.u[j];  // [t_local][d_local]
  __syncthreads();
  union { uint4 v[2]; u16t u[16]; } pk2;
#pragma unroll
  for (int j = 0; j < 16; ++j) pk2.u[j] = tile[(cb + j) * 65 + r];  // read col d=r
  u16t* gt = xT + ((size_t)(b * 256 + d0 + r) * 2048 + t0 + cb);
  *(uint4*)(gt) = pk2.v[0];
  *(uint4*)(gt + 8) = pk2.v[1];
}

// ---------------- prep: W [K][N] fp32 -> WT [N][K] bf16 ---------------------
__global__ __launch_bounds__(256) void prep_w(const float* __restrict__ W,
                                              u16t* __restrict__ WT,
                                              int K, int N) {
  __shared__ u16t tile[64 * 65];
  const int tid = threadIdx.x;
  const int n0 = blockIdx.x * 64, k0 = blockIdx.y * 64;
  const int r = tid >> 2, cb = (tid & 3) << 4;
  const float* gw = W + ((size_t)(k0 + r) * N + n0 + cb);
#pragma unroll
  for (int j = 0; j < 16; j += 4) {
    float4 f = *(const float4*)(gw + j);
    tile[r * 65 + cb + j + 0] = f2bf(f.x);
    tile[r * 65 + cb + j + 1] = f2bf(f.y);
    tile[r * 65 + cb + j + 2] = f2bf(f.z);
    tile[r * 65 + cb + j + 3] = f2bf(f.w);
  }
  __syncthreads();
  union { uint4 v[2]; u16t u[16]; } pk;
#pragma unroll
  for (int j = 0; j < 16; ++j) pk.u[j] = tile[(cb + j) * 65 + r];  // = W[k0+cb+j][n0+r]
  u16t* gt = WT + ((size_t)(n0 + r) * K + k0 + cb);
  *(uint4*)(gt) = pk.v[0];
  *(uint4*)(gt + 8) = pk.v[1];
}

// ---------------- flash attention (strictly causal), writes dec[:,256:512] --
// grid: 1024 blocks = 32 batches x 32 q-tiles (big q-tiles scheduled first)
__global__ __launch_bounds__(256, 2) void attn(u16t* __restrict__ dec,
                                               const u16t* __restrict__ xT) {
  __shared__ char smem[32768 + 4 * 2304];  // shared K/Vt region + per-wave P
  const int tid = threadIdx.x;
  const int wid = tid >> 6, lane = tid & 63, quad = lane >> 4, l15 = lane & 15;
  const int b = blockIdx.x & 31;
  const int qt = 31 - (blockIdx.x >> 5);
  const int q0 = qt << 6;
  char* Pbase = smem + 32768 + wid * 2304;  // 16 rows x 144B

  // Q fragments, scaled by log2(e)/16 (exact-ish; folds softmax scale + exp2)
  short8 qf[8];
  {
    const u16t* qp = dec + ((size_t)(b * 2048 + q0 + wid * 16 + l15) * 512 + quad * 8);
    const float qs = 1.44269504f / 16.0f;
#pragma unroll
    for (int s = 0; s < 8; ++s) {
      union { uint4 v; u16t u[8]; } in;
      union { short8 s8; u16t u[8]; } out;
      in.v = *(const uint4*)(qp + s * 32);
#pragma unroll
      for (int j = 0; j < 8; ++j) out.u[j] = f2bf(bf2f(in.u[j]) * qs);
      qf[s] = out.s8;
    }
  }

  floatx4 o[16];
#pragma unroll
  for (int nt = 0; nt < 16; ++nt) o[nt] = (floatx4){0.f, 0.f, 0.f, 0.f};
  float m_r[4] = {-1e30f, -1e30f, -1e30f, -1e30f};
  float l_r[4] = {0.f, 0.f, 0.f, 0.f};

  for (int kt = 0; kt <= qt; ++kt) {
    const int k0 = kt << 6;
    // stage K tile [64 keys][256 d] bf16, 32 16B-chunks/row, XOR swizzle
#pragma unroll
    for (int i = 0; i < 8; ++i) {
      int c = i * 256 + tid;
      int r = c >> 5, q = (c & 31) ^ (r & 7);
      async_copy16(dec + ((size_t)(b * 2048 + k0 + r) * 512 + q * 8), smem + c * 16);
    }
    __syncthreads();
    // S = (scaled Q) K^T : per wave 16 rows x 64 keys
    floatx4 s4[4];
#pragma unroll
    for (int jn = 0; jn < 4; ++jn) s4[jn] = (floatx4){0.f, 0.f, 0.f, 0.f};
#pragma unroll
    for (int s = 0; s < 8; ++s) {
#pragma unroll
      for (int jn = 0; jn < 4; ++jn) {
        int n = jn * 16 + l15;
        const short8 kb =
            *(const short8*)(smem + ((n * 32 + ((s * 4 + quad) ^ (l15 & 7))) * 16));
        s4[jn] = __builtin_amdgcn_mfma_f32_16x16x32_bf16(qf[s], kb, s4[jn], 0, 0, 0);
      }
    }
    if (kt == qt) {  // diagonal tile: strict mask key_local < row_local
#pragma unroll
      for (int jn = 0; jn < 4; ++jn)
#pragma unroll
        for (int reg = 0; reg < 4; ++reg)
          if (jn * 16 + l15 >= wid * 16 + quad * 4 + reg) s4[jn][reg] = -1e30f;
    }
    // online softmax (exp2 domain)
    float mx[4], al[4], ps[4];
#pragma unroll
    for (int reg = 0; reg < 4; ++reg)
      mx[reg] = fmaxf(fmaxf(s4[0][reg], s4[1][reg]), fmaxf(s4[2][reg], s4[3][reg]));
#pragma unroll
    for (int d = 1; d <= 8; d <<= 1)
#pragma unroll
      for (int reg = 0; reg < 4; ++reg)
        mx[reg] = fmaxf(mx[reg], __shfl_xor(mx[reg], d, 64));
#pragma unroll
    for (int reg = 0; reg < 4; ++reg) {
      float mn = fmaxf(m_r[reg], mx[reg]);
      al[reg] = exp2f(m_r[reg] - mn);
      m_r[reg] = mn;
      ps[reg] = 0.f;
    }
#pragma unroll
    for (int jn = 0; jn < 4; ++jn)
#pragma unroll
      for (int reg = 0; reg < 4; ++reg) {
        float p = exp2f(s4[jn][reg] - m_r[reg]);
        ps[reg] += p;
        *(u16t*)(Pbase + (quad * 4 + reg) * 144 + (jn * 16 + l15) * 2) = f2bf(p);
      }
#pragma unroll
    for (int d = 1; d <= 8; d <<= 1)
#pragma unroll
      for (int reg = 0; reg < 4; ++reg) ps[reg] += __shfl_xor(ps[reg], d, 64);
#pragma unroll
    for (int reg = 0; reg < 4; ++reg) l_r[reg] = l_r[reg] * al[reg] + ps[reg];
#pragma unroll
    for (int nt = 0; nt < 16; ++nt)
#pragma unroll
      for (int reg = 0; reg < 4; ++reg) o[nt][reg] *= al[reg];
    __syncthreads();  // everyone done reading K region
    // stage Vt tile [256 d][64 keys] over the same region (V == K == x)
#pragma unroll
    for (int i = 0; i < 8; ++i) {
      int c = i * 256 + tid;
      int r = c >> 3, q = (c & 7) ^ (r & 7);
      async_copy16(xT + ((size_t)(b * 256 + r) * 2048 + k0 + q * 8), smem + c * 16);
    }
    __syncthreads();
    // O += P V  (P from LDS in A-layout, Vt B-frags contiguous)
#pragma unroll
    for (int s2 = 0; s2 < 2; ++s2) {
      const short8 pa = *(const short8*)(Pbase + l15 * 144 + (s2 * 4 + quad) * 16);
#pragma unroll
      for (int nt = 0; nt < 16; ++nt) {
        int dd = nt * 16 + l15;
        const short8 vb =
            *(const short8*)(smem + ((dd * 8 + ((s2 * 4 + quad) ^ (l15 & 7))) * 16));
        o[nt] = __builtin_amdgcn_mfma_f32_16x16x32_bf16(pa, vb, o[nt], 0, 0, 0);
      }
    }
    __syncthreads();  // done reading Vt before next kt overwrites
  }
  // epilogue: ctx = O/l ; t=0 forced to 0 (matches reference's (t>0) mask)
  float inv[4];
#pragma unroll
  for (int reg = 0; reg < 4; ++reg)
    inv[reg] = (l_r[reg] > 0.f) ? (1.0f / l_r[reg]) : 0.f;
  const int trow = q0 + wid * 16 + quad * 4;
#pragma unroll
  for (int nt = 0; nt < 16; ++nt)
#pragma unroll
    for (int reg = 0; reg < 4; ++reg) {
      float v = ((trow + reg) == 0) ? 0.f : o[nt][reg] * inv[reg];
      dec[(size_t)(b * 2048 + trow + reg) * 512 + 256 + nt * 16 + l15] = f2bf(v);
    }
}

// ---------------- GEMM: C = A[M,K] * BT[N,K]^T + bias ----------------------
// MODE 0: relu -> bf16 row-major [M,N] (h).  MODE 1: fp32 split-write to d_out.
template <int MODE>
__global__ __launch_bounds__(256, 2) void gemm(const u16t* __restrict__ A,
                                               const u16t* __restrict__ BT,
                                               const float* __restrict__ bias,
                                               void* __restrict__ outp,
                                               int N, int K) {
  __shared__ char smem[32768];
  const int tid = threadIdx.x;
  const int lane = tid & 63, wid = tid >> 6, quad = lane >> 4, l15 = lane & 15;
  const int wm = wid >> 1, wn = wid & 1;
  const int m0 = blockIdx.y << 7, n0 = blockIdx.x << 7;
  floatx4 acc[4][4];
#pragma unroll
  for (int mi = 0; mi < 4; ++mi)
#pragma unroll
    for (int jn = 0; jn < 4; ++jn) acc[mi][jn] = (floatx4){0.f, 0.f, 0.f, 0.f};
  const int kit = K >> 6;
  for (int kk = 0; kk < kit; ++kk) {
    const int k0 = kk << 6;
#pragma unroll
    for (int i = 0; i < 4; ++i) {
      int c = i * 256 + tid;
      int r = c >> 3, q = (c & 7) ^ (r & 7);
      async_copy16(A + ((size_t)(m0 + r) * K + k0 + q * 8), smem + c * 16);
    }
#pragma unroll
    for (int i = 0; i < 4; ++i) {
      int c = i * 256 + tid;
      int r = c >> 3, q = (c & 7) ^ (r & 7);
      async_copy16(BT + ((size_t)(n0 + r) * K + k0 + q * 8), smem + 16384 + c * 16);
    }
    __syncthreads();
#pragma unroll
    for (int s2 = 0; s2 < 2; ++s2) {
      short8 af[4], bfr[4];
#pragma unroll
      for (int mi = 0; mi < 4; ++mi) {
        int m = wm * 64 + mi * 16 + l15;
        af[mi] = *(const short8*)(smem + ((m * 8 + ((s2 * 4 + quad) ^ (l15 & 7))) * 16));
      }
#pragma unroll
      for (int jn = 0; jn < 4; ++jn) {
        int n = wn * 64 + jn * 16 + l15;
        bfr[jn] =
            *(const short8*)(smem + 16384 + ((n * 8 + ((s2 * 4 + quad) ^ (l15 & 7))) * 16));
      }
#pragma unroll
      for (int mi = 0; mi < 4; ++mi)
#pragma unroll
        for (int jn = 0; jn < 4; ++jn)
          acc[mi][jn] =
              __builtin_amdgcn_mfma_f32_16x16x32_bf16(af[mi], bfr[jn], acc[mi][jn], 0, 0, 0);
    }
    __syncthreads();
  }
  float bv[4];
#pragma unroll
  for (int jn = 0; jn < 4; ++jn) bv[jn] = bias[n0 + wn * 64 + jn * 16 + l15];
#pragma unroll
  for (int mi = 0; mi < 4; ++mi)
#pragma unroll
    for (int jn = 0; jn < 4; ++jn)
#pragma unroll
      for (int reg = 0; reg < 4; ++reg) {
        int row = m0 + wm * 64 + mi * 16 + quad * 4 + reg;
        int col = n0 + wn * 64 + jn * 16 + l15;
        float v = acc[mi][jn][reg] + bv[jn];
        if (MODE == 0) {
          v = fmaxf(v, 0.f);
          ((u16t*)outp)[(size_t)row * N + col] = f2bf(v);
        } else {
          float* po = (float*)outp;
          if (col < 256) po[(size_t)row * 256 + col] = v;
          else po[16777216u + (size_t)row * 256 + (col - 256)] = v;
        }
      }
}

// ---------------- launch ----------------------------------------------------
extern "C" void kernel_launch(void* const* d_in, const int* in_sizes, int n_in,
                              void* d_out, int out_size, void* d_ws, size_t ws_size,
                              hipStream_t stream) {
  const float* x  = (const float*)d_in[0];
  const float* W1 = (const float*)d_in[1];
  const float* b1 = (const float*)d_in[2];
  const float* W2 = (const float*)d_in[3];
  const float* b2 = (const float*)d_in[4];
  char* ws = (char*)d_ws;
  // ws layout (194 MB): dec 64MB | h 128MB (xT aliases h: dead before gemm1) | WT 2MB
  u16t* dec = (u16t*)ws;                                     // [65536][512] bf16
  u16t* h   = (u16t*)(ws + 67108864ull);                     // [65536][1024] bf16
  u16t* xT  = (u16t*)(ws + 67108864ull);                     // [32][256][2048] bf16
  u16t* W1T = (u16t*)(ws + 67108864ull + 134217728ull);      // [1024][512] bf16
  u16t* W2T = (u16t*)(ws + 67108864ull + 134217728ull + 1048576ull);  // [512][1024]

  prep_x<<<dim3(4, 32, 32), 256, 0, stream>>>(x, dec, xT);
  prep_w<<<dim3(16, 8), 256, 0, stream>>>(W1, W1T, 512, 1024);
  prep_w<<<dim3(8, 16), 256, 0, stream>>>(W2, W2T, 1024, 512);
  attn<<<1024, 256, 0, stream>>>(dec, xT);
  gemm<0><<<dim3(8, 512), 256, 0, stream>>>(dec, W1T, b1, (void*)h, 1024, 512);
  gemm<1><<<dim3(4, 512), 256, 0, stream>>>(h, W2T, b2, d_out, 512, 1024);
}

// Round 2
// 501.420 us; speedup vs baseline: 1.0163x; 1.0163x over previous
//
#include <hip/hip_runtime.h>
#include <stdint.h>

typedef unsigned short u16t;
typedef __attribute__((ext_vector_type(8))) short short8;
typedef __attribute__((ext_vector_type(4))) float floatx4;
typedef __attribute__((ext_vector_type(16))) float floatx16;

__device__ __forceinline__ float bf2f(u16t u) {
  union { unsigned int i; float f; } v; v.i = ((unsigned int)u) << 16; return v.f;
}
__device__ __forceinline__ u16t f2bf(float f) {
  union { float f; unsigned int i; } v; v.f = f;
  unsigned int x = v.i;
  return (u16t)((x + 0x7fffu + ((x >> 16) & 1u)) >> 16);  // RNE, no NaNs here
}
__device__ __forceinline__ void async_copy16(const void* g, void* l) {
  __builtin_amdgcn_global_load_lds(
      (const __attribute__((address_space(1))) void*)g,
      (__attribute__((address_space(3))) void*)l, 16, 0, 0);
}

// ---------------- prep: x fp32 -> dec[:, :256] bf16  +  xT[B][D][T] bf16 ----
__global__ __launch_bounds__(256) void prep_x(const float* __restrict__ x,
                                              u16t* __restrict__ dec,
                                              u16t* __restrict__ xT) {
  __shared__ u16t tile[64 * 65];
  const int tid = threadIdx.x;
  const int b = blockIdx.z, t0 = blockIdx.y * 64, d0 = blockIdx.x * 64;
  const int r = tid >> 2, cb = (tid & 3) << 4;
  const float* gx = x + ((size_t)(b * 2048 + t0 + r) * 256 + d0 + cb);
  union { uint4 v[2]; u16t u[16]; } pk;
#pragma unroll
  for (int j = 0; j < 16; j += 4) {
    float4 f = *(const float4*)(gx + j);
    pk.u[j + 0] = f2bf(f.x); pk.u[j + 1] = f2bf(f.y);
    pk.u[j + 2] = f2bf(f.z); pk.u[j + 3] = f2bf(f.w);
  }
  u16t* gd = dec + ((size_t)(b * 2048 + t0 + r) * 512 + d0 + cb);
  *(uint4*)(gd) = pk.v[0];
  *(uint4*)(gd + 8) = pk.v[1];
#pragma unroll
  for (int j = 0; j < 16; ++j) tile[r * 65 + cb + j] = pk.u[j];
  __syncthreads();
  union { uint4 v[2]; u16t u[16]; } pk2;
#pragma unroll
  for (int j = 0; j < 16; ++j) pk2.u[j] = tile[(cb + j) * 65 + r];
  u16t* gt = xT + ((size_t)(b * 256 + d0 + r) * 2048 + t0 + cb);
  *(uint4*)(gt) = pk2.v[0];
  *(uint4*)(gt + 8) = pk2.v[1];
}

// ---------------- prep: W [K][N] fp32 -> WT [N][K] bf16 ---------------------
__global__ __launch_bounds__(256) void prep_w(const float* __restrict__ W,
                                              u16t* __restrict__ WT,
                                              int K, int N) {
  __shared__ u16t tile[64 * 65];
  const int tid = threadIdx.x;
  const int n0 = blockIdx.x * 64, k0 = blockIdx.y * 64;
  const int r = tid >> 2, cb = (tid & 3) << 4;
  const float* gw = W + ((size_t)(k0 + r) * N + n0 + cb);
#pragma unroll
  for (int j = 0; j < 16; j += 4) {
    float4 f = *(const float4*)(gw + j);
    tile[r * 65 + cb + j + 0] = f2bf(f.x);
    tile[r * 65 + cb + j + 1] = f2bf(f.y);
    tile[r * 65 + cb + j + 2] = f2bf(f.z);
    tile[r * 65 + cb + j + 3] = f2bf(f.w);
  }
  __syncthreads();
  union { uint4 v[2]; u16t u[16]; } pk;
#pragma unroll
  for (int j = 0; j < 16; ++j) pk.u[j] = tile[(cb + j) * 65 + r];
  u16t* gt = WT + ((size_t)(n0 + r) * K + k0 + cb);
  *(uint4*)(gt) = pk.v[0];
  *(uint4*)(gt + 8) = pk.v[1];
}

// ---------------- flash attention v3: 32x32x16 MFMA, S^T / O^T dataflow -----
// Block = 64 q rows. Stage1: S^T = K Q^T (2x2 waves: wk,wq). Stage2: O^T = V^T P^T
// (same wave keeps its q block -> softmax state stays in registers per-lane).
__global__ __launch_bounds__(256, 2) void attn(u16t* __restrict__ dec,
                                               const u16t* __restrict__ xT) {
  __shared__ char smem[75264];
  u16t* Kt = (u16t*)smem;                      // [64 keys][32 chunks of 8d] swizzled
  u16t* Vt = (u16t*)(smem + 32768);            // [256 d][8 chunks of 8keys] swizzled
  u16t* P  = (u16t*)(smem + 65536);            // [64 q][stride 68 keys]
  float* redmax = (float*)(smem + 74240);      // [2][64]
  float* redsum = (float*)(smem + 74752);      // [2][64]
  const int tid = threadIdx.x;
  const int wid = tid >> 6, lane = tid & 63;
  const int l31 = lane & 31, hl = lane >> 5;
  const int b = blockIdx.x & 31;
  const int qt = 31 - (blockIdx.x >> 5);       // heavy tiles first
  const int q0 = qt << 6;
  const int wk = wid >> 1, wq = wid & 1;       // stage1 roles; stage2: wd=wk, q same

  // Q B-frags in registers: B[k=d][n=q], q = q0+wq*32+l31, d = s*16+hl*8+j
  short8 qf[16];
  const int qrow = q0 + wq * 32 + l31;
  {
    const u16t* qp = dec + ((size_t)(b * 2048 + qrow) * 512) + hl * 8;
    const float qs = 1.44269504f / 16.0f;  // log2(e)/sqrt(D)
#pragma unroll
    for (int s = 0; s < 16; ++s) {
      union { uint4 v; u16t u[8]; } in;
      union { short8 s8; u16t u[8]; } ot;
      in.v = *(const uint4*)(qp + s * 16);
#pragma unroll
      for (int j = 0; j < 8; ++j) ot.u[j] = f2bf(bf2f(in.u[j]) * qs);
      qf[s] = ot.s8;
    }
  }

  floatx16 o[4];  // O^T tiles: d = wk*128 + dt*32 + row, q = wq*32 + l31 (col)
#pragma unroll
  for (int i = 0; i < 4; ++i)
#pragma unroll
    for (int r = 0; r < 16; ++r) o[i][r] = 0.f;
  float m_r = -1e30f, l_r = 0.f;  // per-lane state for q = wq*32+l31

  for (int kt = 0; kt <= qt; ++kt) {
    const int k0 = kt << 6;
    __syncthreads();  // A: prev iter's K/V/P reads complete before restage
    // stage K-tile: 2048 chunks; c=(r<<5)|s, source chunk cc = s ^ (r&7)
#pragma unroll
    for (int i = 0; i < 8; ++i) {
      int c = i * 256 + tid;
      int r = c >> 5, cc = (c & 31) ^ (r & 7);
      async_copy16(dec + ((size_t)(b * 2048 + k0 + r) * 512) + cc * 8,
                   (char*)Kt + c * 16);
    }
    // stage V^T-tile: 2048 chunks; c=(r<<3)|s, cc = s ^ (r&7)
#pragma unroll
    for (int i = 0; i < 8; ++i) {
      int c = i * 256 + tid;
      int r = c >> 3, cc = (c & 7) ^ (r & 7);
      async_copy16(xT + ((size_t)(b * 256 + r) * 2048) + k0 + cc * 8,
                   (char*)Vt + c * 16);
    }
    __syncthreads();  // B: staging visible

    // stage 1: S^T tile (32 keys x 32 q): A = K[m=key][k=d], B = Q^T
    floatx16 st;
#pragma unroll
    for (int r = 0; r < 16; ++r) st[r] = 0.f;
    const int krow = wk * 32 + l31;
#pragma unroll
    for (int s = 0; s < 16; ++s) {
      int slot = (s * 2 + hl) ^ (krow & 7);
      short8 kf = *(const short8*)((char*)Kt + (krow * 32 + slot) * 16);
      st = __builtin_amdgcn_mfma_f32_32x32x16_bf16(kf, qf[s], st, 0, 0, 0);
    }
    if (kt == qt) {  // strict causal: mask key_loc >= q_loc
      const int q_loc = wq * 32 + l31;
#pragma unroll
      for (int r = 0; r < 16; ++r) {
        int key_loc = wk * 32 + (r & 3) + 8 * (r >> 2) + 4 * hl;
        if (key_loc >= q_loc) st[r] = -1e30f;
      }
    }
    // softmax: per-lane (fixed q) max over this wave's 32 keys
    float mx = st[0];
#pragma unroll
    for (int r = 1; r < 16; ++r) mx = fmaxf(mx, st[r]);
    mx = fmaxf(mx, __shfl_xor(mx, 32, 64));
    if (lane < 32) redmax[wk * 64 + wq * 32 + lane] = mx;
    __syncthreads();  // C: partial max visible
    float mo = redmax[(1 - wk) * 64 + wq * 32 + l31];
    float mn = fmaxf(fmaxf(m_r, mx), mo);
    float al = exp2f(m_r - mn);
    m_r = mn;
    float psum = 0.f;
    u16t pb[16];
#pragma unroll
    for (int r = 0; r < 16; ++r) {
      float p = exp2f(st[r] - mn);
      psum += p;
      pb[r] = f2bf(p);
    }
    psum += __shfl_xor(psum, 32, 64);
    // P pack: rows of S^T (keys) come 4-consecutive per reg-group -> b64 writes
#pragma unroll
    for (int g = 0; g < 4; ++g) {
      union { uint2 v; u16t u[4]; } w;
#pragma unroll
      for (int e = 0; e < 4; ++e) w.u[e] = pb[g * 4 + e];
      *(uint2*)((char*)P +
                ((size_t)(wq * 32 + l31) * 68 + wk * 32 + g * 8 + hl * 4) * 2) = w.v;
    }
    if (lane < 32) redsum[wk * 64 + wq * 32 + lane] = psum;
    __syncthreads();  // D: P + partial sums visible
    float so = redsum[(1 - wk) * 64 + wq * 32 + l31];
    l_r = l_r * al + psum + so;

    // stage 2: O^T += V^T P^T. Same lane-q as stage 1 -> alpha is in-register.
#pragma unroll
    for (int dt = 0; dt < 4; ++dt)
#pragma unroll
      for (int r = 0; r < 16; ++r) o[dt][r] *= al;
#pragma unroll
    for (int ks = 0; ks < 4; ++ks) {
      short8 pf = *(const short8*)((char*)P +
                                   ((size_t)(wq * 32 + l31) * 68 + ks * 16 + hl * 8) * 2);
#pragma unroll
      for (int dt = 0; dt < 4; ++dt) {
        int drow = wk * 128 + dt * 32 + l31;
        int slot = (ks * 2 + hl) ^ (drow & 7);
        short8 vf = *(const short8*)((char*)Vt + (drow * 8 + slot) * 16);
        o[dt] = __builtin_amdgcn_mfma_f32_32x32x16_bf16(vf, pf, o[dt], 0, 0, 0);
      }
    }
  }
  // epilogue: ctx = O/l, t=0 row forced to zero; O^T rows (d) pack b64
  const float inv = (l_r > 0.f) ? 1.0f / l_r : 0.f;
  const int qg = q0 + wq * 32 + l31;
  u16t* outp = dec + ((size_t)(b * 2048 + qg) * 512) + 256;
#pragma unroll
  for (int dt = 0; dt < 4; ++dt)
#pragma unroll
    for (int g = 0; g < 4; ++g) {
      union { uint2 v; u16t u[4]; } w;
#pragma unroll
      for (int e = 0; e < 4; ++e) {
        float val = (qg == 0) ? 0.f : o[dt][g * 4 + e] * inv;
        w.u[e] = f2bf(val);
      }
      *(uint2*)(outp + wk * 128 + dt * 32 + g * 8 + hl * 4) = w.v;
    }
}

// ---------------- GEMM v2: C = A[M,K] * BT[N,K]^T + bias --------------------
// block 128m x 256n, wave tile 64x128; operand-swapped mfma -> transposed C
// fragments -> 4 consecutive cols per quad-reg-group -> packed stores.
template <int MODE>
__global__ __launch_bounds__(256, 2) void gemm(const u16t* __restrict__ A,
                                               const u16t* __restrict__ BT,
                                               const float* __restrict__ bias,
                                               void* __restrict__ outp,
                                               int N, int K) {
  __shared__ char smem[49152];  // A-tile 16KB | B-tile 32KB
  const int tid = threadIdx.x;
  const int lane = tid & 63, wid = tid >> 6, quad = lane >> 4, l15 = lane & 15;
  const int wm = wid >> 1, wn = wid & 1;
  const int m0 = blockIdx.y << 7, n0 = blockIdx.x << 8;
  floatx4 acc[4][8];
#pragma unroll
  for (int mi = 0; mi < 4; ++mi)
#pragma unroll
    for (int jn = 0; jn < 8; ++jn) acc[mi][jn] = (floatx4){0.f, 0.f, 0.f, 0.f};
  const int kit = K >> 6;
  for (int kk = 0; kk < kit; ++kk) {
    const int k0 = kk << 6;
#pragma unroll
    for (int i = 0; i < 4; ++i) {  // A: 128 rows x 8 chunks
      int c = i * 256 + tid;
      int r = c >> 3, q = (c & 7) ^ (r & 7);
      async_copy16(A + ((size_t)(m0 + r) * K) + k0 + q * 8, smem + c * 16);
    }
#pragma unroll
    for (int i = 0; i < 8; ++i) {  // B: 256 rows x 8 chunks
      int c = i * 256 + tid;
      int r = c >> 3, q = (c & 7) ^ (r & 7);
      async_copy16(BT + ((size_t)(n0 + r) * K) + k0 + q * 8, smem + 16384 + c * 16);
    }
    __syncthreads();
#pragma unroll
    for (int s2 = 0; s2 < 2; ++s2) {
      short8 af[4], bfr[8];
#pragma unroll
      for (int mi = 0; mi < 4; ++mi) {
        int m = wm * 64 + mi * 16 + l15;
        af[mi] = *(const short8*)(smem + ((m * 8 + ((s2 * 4 + quad) ^ (l15 & 7))) * 16));
      }
#pragma unroll
      for (int jn = 0; jn < 8; ++jn) {
        int n = wn * 128 + jn * 16 + l15;
        bfr[jn] = *(const short8*)(smem + 16384 +
                                   ((n * 8 + ((s2 * 4 + quad) ^ (l15 & 7))) * 16));
      }
#pragma unroll
      for (int mi = 0; mi < 4; ++mi)
#pragma unroll
        for (int jn = 0; jn < 8; ++jn)  // swapped operands -> C^T fragments
          acc[mi][jn] = __builtin_amdgcn_mfma_f32_16x16x32_bf16(
              bfr[jn], af[mi], acc[mi][jn], 0, 0, 0);
    }
    __syncthreads();
  }
  // epilogue: lane holds C[row = m0+wm*64+mi*16+l15][cols n-base + quad*4 + 0..3]
#pragma unroll
  for (int jn = 0; jn < 8; ++jn) {
    const float4 bv = *(const float4*)(bias + n0 + wn * 128 + jn * 16 + quad * 4);
#pragma unroll
    for (int mi = 0; mi < 4; ++mi) {
      const int row = m0 + wm * 64 + mi * 16 + l15;
      const int ncol = wn * 128 + jn * 16 + quad * 4;
      float v0 = acc[mi][jn][0] + bv.x;
      float v1 = acc[mi][jn][1] + bv.y;
      float v2 = acc[mi][jn][2] + bv.z;
      float v3 = acc[mi][jn][3] + bv.w;
      if (MODE == 0) {
        union { uint2 v; u16t u[4]; } w;
        w.u[0] = f2bf(fmaxf(v0, 0.f)); w.u[1] = f2bf(fmaxf(v1, 0.f));
        w.u[2] = f2bf(fmaxf(v2, 0.f)); w.u[3] = f2bf(fmaxf(v3, 0.f));
        *(uint2*)((u16t*)outp + (size_t)row * N + n0 + ncol) = w.v;
      } else {
        float* po = (float*)outp + ((size_t)(n0 >> 8)) * 16777216ull;
        *(float4*)(po + (size_t)row * 256 + ncol) = (float4){v0, v1, v2, v3};
      }
    }
  }
}

// ---------------- launch ----------------------------------------------------
extern "C" void kernel_launch(void* const* d_in, const int* in_sizes, int n_in,
                              void* d_out, int out_size, void* d_ws, size_t ws_size,
                              hipStream_t stream) {
  const float* x  = (const float*)d_in[0];
  const float* W1 = (const float*)d_in[1];
  const float* b1 = (const float*)d_in[2];
  const float* W2 = (const float*)d_in[3];
  const float* b2 = (const float*)d_in[4];
  char* ws = (char*)d_ws;
  u16t* dec = (u16t*)ws;                                     // [65536][512] bf16
  u16t* h   = (u16t*)(ws + 67108864ull);                     // [65536][1024] bf16
  u16t* xT  = (u16t*)(ws + 67108864ull);                     // [32][256][2048] (dead before gemm0 output)
  u16t* W1T = (u16t*)(ws + 67108864ull + 134217728ull);      // [1024][512]
  u16t* W2T = (u16t*)(ws + 67108864ull + 134217728ull + 1048576ull);  // [512][1024]

  prep_x<<<dim3(4, 32, 32), 256, 0, stream>>>(x, dec, xT);
  prep_w<<<dim3(16, 8), 256, 0, stream>>>(W1, W1T, 512, 1024);
  prep_w<<<dim3(8, 16), 256, 0, stream>>>(W2, W2T, 1024, 512);
  attn<<<1024, 256, 0, stream>>>(dec, xT);
  gemm<0><<<dim3(4, 512), 256, 0, stream>>>(dec, W1T, b1, (void*)h, 1024, 512);
  gemm<1><<<dim3(2, 512), 256, 0, stream>>>(h, W2T, b2, d_out, 512, 1024);
}